// Round 4
// baseline (1763.577 us; speedup 1.0000x reference)
//
#include <hip/hip_runtime.h>

#define BATCH   16384
#define NSTEPS  100
#define DT_     0.01f
#define SQRTDT  0.1f
#define SIGMA0_ 0.5f

__global__ void zero_out_kernel(float* out) {
    if (threadIdx.x == 0) out[0] = 0.0f;
}

// Precompute v[i][m][k] = W1_m[0][k] * t_i + b1_m[k]  (t accumulated like the
// reference: t_0 = 0, t += DT each step). Layout: vtab[(i*2 + m)*64 + k].
__global__ void vtab_kernel(const float* __restrict__ zW1, const float* __restrict__ zb1,
                            const float* __restrict__ qW1, const float* __restrict__ qb1,
                            float* __restrict__ vtab) {
    int k = threadIdx.x & 63;
    int m = threadIdx.x >> 6;                 // 0 = z, 1 = q
    const float* W1 = m ? qW1 : zW1;
    const float* b1 = m ? qb1 : zb1;
    float A = W1[k], C = b1[k];
    float t = 0.0f;
    for (int i = 0; i < NSTEPS; ++i) {
        vtab[(i * 2 + m) * 64 + k] = fmaf(A, t, C);
        t += DT_;
    }
}

// Layout: lane (tid&63) = path within block; 8 waves per block.
// Waves 0-3: z-MLP, j-slice [16w, 16w+16).  Waves 4-7: q-MLP, same slices.
// All weight addresses wave-uniform -> s_load; 2048 waves = 2 waves/SIMD for
// scalar-load latency hiding. One barrier/step (double-buffered LDS exchange).
__launch_bounds__(512)
__global__ void deepbsde_kernel(
    const float* __restrict__ y0,  const float* __restrict__ Y0,
    const float* __restrict__ zW1, const float* __restrict__ zb1,
    const float* __restrict__ zW2, const float* __restrict__ zb2,
    const float* __restrict__ zW3, const float* __restrict__ zb3,
    const float* __restrict__ qW1, const float* __restrict__ qb1,
    const float* __restrict__ qW2, const float* __restrict__ qb2,
    const float* __restrict__ qW3, const float* __restrict__ qb3,
    const float* __restrict__ dW,  const float* __restrict__ dZ,
    const float* __restrict__ vtab,
    float* __restrict__ out)
{
    __shared__ float4 pz[2][4][64];   // z layer-3 partials (z0,z1,z2,-)
    __shared__ float  pq[2][4][64];   // q layer-3 partials

    const int tid  = threadIdx.x;
    const int lane = tid & 63;
    const int w    = tid >> 6;                                    // 0..7
    const int sel  = w >> 2;                                      // 0=z, 1=q
    const int ws4  = w & 3;
    const int jb   = __builtin_amdgcn_readfirstlane(ws4 << 4);    // uniform

    const int p = (blockIdx.x << 6) + lane;                       // path id

    // uniform (SGPR) weight pointers for this wave's MLP + j-slice
    const float* __restrict__ W2p  = (sel ? qW2 : zW2) + jb;      // W2p[k*64+j]
    const float* __restrict__ B1p  = (sel ? qW1 : zW1) + 64;      // B1p[k]
    const float* __restrict__ b2p  = (sel ? qb2 : zb2) + jb;
    const float* __restrict__ zw3p = zW3 + jb * 3;
    const float* __restrict__ qw3p = qW3 + jb;
    const float* __restrict__ vbase = vtab + (sel ? 64 : 0);

    float y  = y0[0];
    float Yv = Y0[0];
    float acc = 0.0f;
    const float zb30 = zb3[0], zb31 = zb3[1], zb32 = zb3[2], qb30 = qb3[0];

    const float* dWp = dW + (size_t)p * 3;
    const float* dZp = dZ + (size_t)p * 3;

#pragma unroll 1
    for (int i = 0; i < NSTEPS; ++i) {
        float nw0 = dWp[0], nw1 = dWp[1], nw2 = dWp[2];
        float nz0 = dZp[0], nz1 = dZp[1], nz2 = dZp[2];
        dWp += (size_t)BATCH * 3;
        dZp += (size_t)BATCH * 3;

        const float* __restrict__ vr = vbase + i * 128;

        float a[16];
#pragma unroll
        for (int j = 0; j < 16; ++j) a[j] = b2p[j];

        // fused layer1 (h recomputed per k from scalar B_k, v_k) + layer2 slice
#pragma unroll 4
        for (int k = 0; k < 64; ++k) {
            float h = fmaxf(fmaf(B1p[k], y, vr[k]), 0.0f);
            const float* __restrict__ wr = W2p + k * 64;
#pragma unroll
            for (int j = 0; j < 16; ++j) a[j] = fmaf(h, wr[j], a[j]);
        }

        // layer-3 partials over owned j-slice
        const int b = i & 1;
        if (sel == 0) {
            float oz0 = 0.0f, oz1 = 0.0f, oz2 = 0.0f;
#pragma unroll
            for (int j = 0; j < 16; ++j) {
                float h = fmaxf(a[j], 0.0f);
                oz0 = fmaf(h, zw3p[j * 3 + 0], oz0);
                oz1 = fmaf(h, zw3p[j * 3 + 1], oz1);
                oz2 = fmaf(h, zw3p[j * 3 + 2], oz2);
            }
            pz[b][ws4][lane] = make_float4(oz0, oz1, oz2, 0.0f);
        } else {
            float oq = 0.0f;
#pragma unroll
            for (int j = 0; j < 16; ++j) {
                float h = fmaxf(a[j], 0.0f);
                oq = fmaf(h, qw3p[j], oq);
            }
            pq[b][ws4][lane] = oq;
        }
        __syncthreads();

        float4 c0 = pz[b][0][lane], c1 = pz[b][1][lane];
        float4 c2 = pz[b][2][lane], c3 = pz[b][3][lane];
        float q0 = pq[b][0][lane], q1 = pq[b][1][lane];
        float q2 = pq[b][2][lane], q3 = pq[b][3][lane];

        float z0 = ((c0.x + c1.x) + (c2.x + c3.x)) + zb30;
        float z1 = ((c0.y + c1.y) + (c2.y + c3.y)) + zb31;
        float z2 = ((c0.z + c1.z) + (c2.z + c3.z)) + zb32;
        float q  = ((q0 + q1) + (q2 + q3)) + qb30;

        float dw0 = SQRTDT * nw0, dw1 = SQRTDT * nw1, dw2 = SQRTDT * nw2;
        float dz0 = SQRTDT * nz0, dz1 = SQRTDT * nz1, dz2 = SQRTDT * nz2;

        float zdw = fmaf(z2, dw2, fmaf(z1, dw1, z0 * dw0));
        float zdz = fmaf(z2, dz2, fmaf(z1, dz1, z0 * dz0));

        float f = 0.5f * q * q;
        Yv = Yv - f * DT_ + zdw;
        float r = zdw - zdz;            // residual: (Y - f*DT) cancels
        acc = fmaf(r, r, acc);          // identical across all 8 waves
        y = y + q * DT_ + SIGMA0_ * (dw0 + dw1 + dw2);
    }

    float d = Yv - y * y;
    acc = fmaf(d, d, acc);

    // all waves hold identical acc -> wave 0 contributes once
    if (w == 0) {
        float val = acc;
#pragma unroll
        for (int off = 1; off < 64; off <<= 1) val += __shfl_xor(val, off);
        if (lane == 0) atomicAdd(out, val * (1.0f / BATCH));
    }
}

extern "C" void kernel_launch(void* const* d_in, const int* in_sizes, int n_in,
                              void* d_out, int out_size, void* d_ws, size_t ws_size,
                              hipStream_t stream)
{
    float* vtab = (float*)d_ws;   // 100*2*64*4 = 51200 B
    zero_out_kernel<<<1, 64, 0, stream>>>((float*)d_out);
    vtab_kernel<<<1, 128, 0, stream>>>(
        (const float*)d_in[2], (const float*)d_in[3],
        (const float*)d_in[8], (const float*)d_in[9], vtab);
    deepbsde_kernel<<<256, 512, 0, stream>>>(
        (const float*)d_in[0],  (const float*)d_in[1],
        (const float*)d_in[2],  (const float*)d_in[3],
        (const float*)d_in[4],  (const float*)d_in[5],
        (const float*)d_in[6],  (const float*)d_in[7],
        (const float*)d_in[8],  (const float*)d_in[9],
        (const float*)d_in[10], (const float*)d_in[11],
        (const float*)d_in[12], (const float*)d_in[13],
        (const float*)d_in[14], (const float*)d_in[15],
        vtab, (float*)d_out);
}

// Round 5
// 250.741 us; speedup vs baseline: 7.0334x; 7.0334x over previous
//
#include <hip/hip_runtime.h>
#include <hip/hip_bf16.h>

#define BATCH   16384
#define NSTEPS  100
#define DT_     0.01f
#define SQRTDT  0.1f
#define SIGMA0_ 0.5f

typedef short bf16x8 __attribute__((ext_vector_type(8)));
typedef float f32x4  __attribute__((ext_vector_type(4)));

__global__ void zero_out_kernel(float* out) { if (threadIdx.x == 0) out[0] = 0.0f; }

static __device__ __forceinline__ unsigned short bf16bits(float x) {
    union { __hip_bfloat16 h; unsigned short u; } cv;
    cv.h = __float2bfloat16(x);
    return cv.u;
}
static __device__ __forceinline__ unsigned packbf16(float a, float b) {
    union { __hip_bfloat162 h; unsigned u; } cv;
    cv.h = __float22bfloat162_rn(make_float2(a, b));
    return cv.u;
}

// Block: 512 threads = 8 waves, 64 paths (path = lane). Wave w: MLP s=w>>2,
// group g=w&3. Phases per step: E (h1 slice, consts in SGPR) -> M (MFMA
// layer-2, W2 resident in VGPR B-frags) -> L (layer-3 partials) -> C (combine
// + path update). W2 never touches memory inside the loop.
__launch_bounds__(512)
__global__ void deepbsde_kernel(
    const float* __restrict__ y0,  const float* __restrict__ Y0,
    const float* __restrict__ zW1, const float* __restrict__ zb1,
    const float* __restrict__ zW2, const float* __restrict__ zb2,
    const float* __restrict__ zW3, const float* __restrict__ zb3,
    const float* __restrict__ qW1, const float* __restrict__ qb1,
    const float* __restrict__ qW2, const float* __restrict__ qb2,
    const float* __restrict__ qW3, const float* __restrict__ qb3,
    const float* __restrict__ dW,  const float* __restrict__ dZ,
    float* __restrict__ out)
{
    __shared__ uint4  h1v[1152];     // [s][p] rows of 9 uint4 (72 bf16, padded) = 18.4 KB
    __shared__ uint4  a2v[1152];     // relu(layer2) bf16, same shape            = 18.4 KB
    __shared__ float4 part[64 * 5];  // [p][slot]: 0..3 z-partials, 4 = q packed =  5 KB
    __shared__ float4 w3t[64];       // (zW3[n][0..2], qW3[n])                   =  1 KB

    const int tid  = threadIdx.x;
    const int lane = tid & 63;
    const int w    = tid >> 6;       // 0..7
    const int s    = w >> 2;         // 0 = z-MLP, 1 = q-MLP
    const int g    = w & 3;          // k-quarter (E) / path-group (M) / n-quarter (L)
    const int ln15 = lane & 15, q4 = lane >> 4;
    const int p    = lane;           // path within block
    const int pg   = (blockIdx.x << 6) + p;

    if (tid < 64)
        w3t[tid] = make_float4(zW3[tid*3], zW3[tid*3+1], zW3[tid*3+2], qW3[tid]);

    const float* __restrict__ W1s = s ? qW1 : zW1;
    const float* __restrict__ b1s = s ? qb1 : zb1;
    const float* __restrict__ W2s = s ? qW2 : zW2;
    const float* __restrict__ b2s = s ? qb2 : zb2;

    // layer-1 consts for this wave's k-quarter (wave-uniform -> SGPR)
    float Ak[16], Bk[16], Ck[16];
#pragma unroll
    for (int j = 0; j < 16; ++j) {
        Ak[j] = W1s[g*16 + j];          // W1[0][k]
        Bk[j] = W1s[64 + g*16 + j];     // W1[1][k]
        Ck[j] = b1s[g*16 + j];          // b1[k]
    }

    // resident W2 B-frags: B[k = 32f + q4*8 + j][n = 16tN + ln15]
    bf16x8 Bf[4][2];
#pragma unroll
    for (int tN = 0; tN < 4; ++tN)
#pragma unroll
        for (int f = 0; f < 2; ++f)
#pragma unroll
            for (int j = 0; j < 8; ++j)
                Bf[tN][f][j] = (short)bf16bits(W2s[(32*f + q4*8 + j)*64 + 16*tN + ln15]);

    float b2v[4];
#pragma unroll
    for (int tN = 0; tN < 4; ++tN) b2v[tN] = b2s[16*tN + ln15];

    const int eIdx = (s*64 + p)*9 + g*2;              // E write (uint4 units)
    const int aIdx = (s*64 + 16*g + ln15)*9 + q4;     // M A-frag read; +4 for f=1
    const int wrI  = (s*64 + 16*g + q4*4)*72 + ln15;  // M a2 write (short units)
    unsigned short* a2s = (unsigned short*)a2v;

    float y = y0[0], Yv = Y0[0], t = 0.0f, acc = 0.0f;
    const float zb30 = zb3[0], zb31 = zb3[1], zb32 = zb3[2], qb30 = qb3[0];

    const float* dWp = dW + (size_t)pg * 3;
    const float* dZp = dZ + (size_t)pg * 3;

    __syncthreads();

#pragma unroll 1
    for (int i = 0; i < NSTEPS; ++i) {
        // noise for this step's epilogue — in flight across 3 phases
        float nw0 = dWp[0], nw1 = dWp[1], nw2 = dWp[2];
        float nz0 = dZp[0], nz1 = dZp[1], nz2 = dZp[2];
        dWp += (size_t)BATCH * 3;  dZp += (size_t)BATCH * 3;

        // ---- E: h1 slice for (path p, MLP s, k in [16g,16g+16)) ----
        float hv[16];
#pragma unroll
        for (int j = 0; j < 16; ++j) {
            float v = fmaf(Ak[j], t, Ck[j]);
            hv[j] = fmaxf(fmaf(Bk[j], y, v), 0.0f);
        }
        h1v[eIdx]     = make_uint4(packbf16(hv[0],hv[1]),   packbf16(hv[2],hv[3]),
                                   packbf16(hv[4],hv[5]),   packbf16(hv[6],hv[7]));
        h1v[eIdx + 1] = make_uint4(packbf16(hv[8],hv[9]),   packbf16(hv[10],hv[11]),
                                   packbf16(hv[12],hv[13]), packbf16(hv[14],hv[15]));
        __syncthreads();   // A

        // ---- M: MFMA layer-2, paths 16g..16g+15, all 64 neurons ----
        bf16x8 a0 = __builtin_bit_cast(bf16x8, h1v[aIdx]);
        bf16x8 a1 = __builtin_bit_cast(bf16x8, h1v[aIdx + 4]);
#pragma unroll
        for (int tN = 0; tN < 4; ++tN) {
            f32x4 d = { b2v[tN], b2v[tN], b2v[tN], b2v[tN] };
            d = __builtin_amdgcn_mfma_f32_16x16x32_bf16(a0, Bf[tN][0], d, 0, 0, 0);
            d = __builtin_amdgcn_mfma_f32_16x16x32_bf16(a1, Bf[tN][1], d, 0, 0, 0);
#pragma unroll
            for (int r = 0; r < 4; ++r)
                a2s[wrI + r*72 + tN*16] = bf16bits(fmaxf(d[r], 0.0f));
        }
        __syncthreads();   // B

        // ---- L: layer-3 partials over n in [16g,16g+16) ----
        uint4 u0 = a2v[eIdx], u1 = a2v[eIdx + 1];
        unsigned uu[8] = {u0.x,u0.y,u0.z,u0.w,u1.x,u1.y,u1.z,u1.w};
        float v16[16];
#pragma unroll
        for (int m = 0; m < 8; ++m) {
            union {unsigned u; float f;} lo, hi;
            lo.u = uu[m] << 16; hi.u = uu[m] & 0xFFFF0000u;
            v16[2*m] = lo.f; v16[2*m+1] = hi.f;
        }
        if (s == 0) {
            float oz0 = 0, oz1 = 0, oz2 = 0;
#pragma unroll
            for (int j = 0; j < 16; ++j) {
                float4 ww = w3t[g*16 + j];
                oz0 = fmaf(v16[j], ww.x, oz0);
                oz1 = fmaf(v16[j], ww.y, oz1);
                oz2 = fmaf(v16[j], ww.z, oz2);
            }
            part[p*5 + g] = make_float4(oz0, oz1, oz2, 0.0f);
        } else {
            float oq = 0;
#pragma unroll
            for (int j = 0; j < 16; ++j)
                oq = fmaf(v16[j], w3t[g*16 + j].w, oq);
            ((float*)&part[p*5 + 4])[g] = oq;   // 4 q-waves fill 4 components
        }
        __syncthreads();   // C

        // ---- C: combine + epilogue (redundant on all 8 waves) ----
        float4 c0 = part[p*5+0], c1 = part[p*5+1], c2 = part[p*5+2], c3 = part[p*5+3];
        float4 cq = part[p*5+4];
        float z0 = ((c0.x+c1.x)+(c2.x+c3.x)) + zb30;
        float z1 = ((c0.y+c1.y)+(c2.y+c3.y)) + zb31;
        float z2 = ((c0.z+c1.z)+(c2.z+c3.z)) + zb32;
        float q  = ((cq.x+cq.y)+(cq.z+cq.w)) + qb30;

        float dw0 = SQRTDT*nw0, dw1 = SQRTDT*nw1, dw2 = SQRTDT*nw2;
        float dz0 = SQRTDT*nz0, dz1 = SQRTDT*nz1, dz2 = SQRTDT*nz2;
        float zdw = fmaf(z2, dw2, fmaf(z1, dw1, z0*dw0));
        float zdz = fmaf(z2, dz2, fmaf(z1, dz1, z0*dz0));
        float f = 0.5f*q*q;
        Yv = Yv - f*DT_ + zdw;
        float r = zdw - zdz;             // residual: (Y - f*DT) cancels
        acc = fmaf(r, r, acc);
        y = y + q*DT_ + SIGMA0_*(dw0 + dw1 + dw2);
        t += DT_;
    }

    float dterm = Yv - y*y;
    acc = fmaf(dterm, dterm, acc);

    if (w == 0) {                        // all waves hold identical acc
        float val = acc;
#pragma unroll
        for (int off = 1; off < 64; off <<= 1) val += __shfl_xor(val, off);
        if (lane == 0) atomicAdd(out, val * (1.0f / BATCH));
    }
}

extern "C" void kernel_launch(void* const* d_in, const int* in_sizes, int n_in,
                              void* d_out, int out_size, void* d_ws, size_t ws_size,
                              hipStream_t stream)
{
    zero_out_kernel<<<1, 64, 0, stream>>>((float*)d_out);
    deepbsde_kernel<<<256, 512, 0, stream>>>(
        (const float*)d_in[0],  (const float*)d_in[1],
        (const float*)d_in[2],  (const float*)d_in[3],
        (const float*)d_in[4],  (const float*)d_in[5],
        (const float*)d_in[6],  (const float*)d_in[7],
        (const float*)d_in[8],  (const float*)d_in[9],
        (const float*)d_in[10], (const float*)d_in[11],
        (const float*)d_in[12], (const float*)d_in[13],
        (const float*)d_in[14], (const float*)d_in[15],
        (float*)d_out);
}

// Round 6
// 211.131 us; speedup vs baseline: 8.3530x; 1.1876x over previous
//
#include <hip/hip_runtime.h>
#include <hip/hip_bf16.h>

#define BATCH   16384
#define NSTEPS  100
#define DT_     0.01f
#define SQRTDT  0.1f
#define SIGMA0_ 0.5f

typedef short bf16x8 __attribute__((ext_vector_type(8)));
typedef float f32x4  __attribute__((ext_vector_type(4)));

__global__ void zero_out_kernel(float* out) { if (threadIdx.x == 0) out[0] = 0.0f; }

static __device__ __forceinline__ unsigned packbf16(float a, float b) {
    union { __hip_bfloat162 h; unsigned u; } cv;
    cv.h = __float22bfloat162_rn(make_float2(a, b));
    return cv.u;
}
static __device__ __forceinline__ unsigned short bf16bits(float x) {
    union { __hip_bfloat16 h; unsigned short u; } cv;
    cv.h = __float2bfloat16(x);
    return cv.u;
}

// sum over the 16-lane DPP row (lanes sharing lane>>4), replicated to all lanes
template<int CTRL>
static __device__ __forceinline__ float ror_add(float x) {
    int yi = __builtin_amdgcn_update_dpp(0, __builtin_bit_cast(int, x),
                                         CTRL, 0xF, 0xF, true);
    return x + __builtin_bit_cast(float, yi);
}
static __device__ __forceinline__ float rowsum16(float x) {
    x = ror_add<0x121>(x);   // row_ror:1
    x = ror_add<0x122>(x);   // row_ror:2
    x = ror_add<0x124>(x);   // row_ror:4
    x = ror_add<0x128>(x);   // row_ror:8
    return x;
}

// Block: 512 thr = 8 waves, 64 paths (path = lane). Wave w: MLP s=w>>2,
// path-group g=w&3. Per step: h1 built directly in A-frag regs (layer-1
// consts live in lane VGPRs, y fetched by one shfl), 8 resident-W2 MFMAs,
// layer-3 partials reduced across the 16-lane DPP row, one 2.5KB LDS
// exchange + ONE barrier, epilogue redundant on all waves.
__launch_bounds__(512)
__global__ void deepbsde_kernel(
    const float* __restrict__ y0,  const float* __restrict__ Y0,
    const float* __restrict__ zW1, const float* __restrict__ zb1,
    const float* __restrict__ zW2, const float* __restrict__ zb2,
    const float* __restrict__ zW3, const float* __restrict__ zb3,
    const float* __restrict__ qW1, const float* __restrict__ qb1,
    const float* __restrict__ qW2, const float* __restrict__ qb2,
    const float* __restrict__ qW3, const float* __restrict__ qb3,
    const float* __restrict__ dW,  const float* __restrict__ dZ,
    float* __restrict__ out)
{
    __shared__ float4 pzs[2][64];   // per-path (z0,z1,z2,-), double-buffered
    __shared__ float  pqs[2][64];   // per-path q partial

    const int tid  = threadIdx.x;
    const int lane = tid & 63;
    const int w    = tid >> 6;       // 0..7
    const int s    = w >> 2;         // 0 = z-MLP, 1 = q-MLP
    const int g    = w & 3;          // path-group: paths [16g, 16g+16)
    const int ln15 = lane & 15, q4 = lane >> 4;
    const int pg   = (blockIdx.x << 6) + lane;

    const float* __restrict__ W1s = s ? qW1 : zW1;
    const float* __restrict__ b1s = s ? qb1 : zb1;
    const float* __restrict__ W2s = s ? qW2 : zW2;
    const float* __restrict__ b2s = s ? qb2 : zb2;

    // layer-1 consts for exactly this lane's A-frag k indices: k = 32f+q4*8+j
    float A1[16], B1c[16], C1[16];
#pragma unroll
    for (int f = 0; f < 2; ++f)
#pragma unroll
        for (int j = 0; j < 8; ++j) {
            int k = 32*f + q4*8 + j;
            A1[f*8+j]  = W1s[k];        // W1[0][k]
            B1c[f*8+j] = W1s[64 + k];   // W1[1][k]
            C1[f*8+j]  = b1s[k];        // b1[k]
        }

    // resident W2 B-frags (layout verified in R5): B[k=32f+q4*8+j][n=16tN+ln15]
    bf16x8 Bf[4][2];
#pragma unroll
    for (int tN = 0; tN < 4; ++tN)
#pragma unroll
        for (int f = 0; f < 2; ++f)
#pragma unroll
            for (int j = 0; j < 8; ++j)
                Bf[tN][f][j] = (short)bf16bits(W2s[(32*f + q4*8 + j)*64 + 16*tN + ln15]);

    float b2v[4];
#pragma unroll
    for (int tN = 0; tN < 4; ++tN) b2v[tN] = b2s[16*tN + ln15];

    // layer-3 weights for this lane's D columns n = 16tN + ln15
    float w3r[3][4], w3q[4];
    if (s == 0) {
#pragma unroll
        for (int tN = 0; tN < 4; ++tN) {
            w3r[0][tN] = zW3[(16*tN + ln15)*3 + 0];
            w3r[1][tN] = zW3[(16*tN + ln15)*3 + 1];
            w3r[2][tN] = zW3[(16*tN + ln15)*3 + 2];
        }
    } else {
#pragma unroll
        for (int tN = 0; tN < 4; ++tN) w3q[tN] = qW3[16*tN + ln15];
    }

    float y = y0[0], Yv = Y0[0], t = 0.0f, acc = 0.0f;
    const float zb30 = zb3[0], zb31 = zb3[1], zb32 = zb3[2], qb30 = qb3[0];

    const float* dWp = dW + (size_t)pg * 3;
    const float* dZp = dZ + (size_t)pg * 3;

#pragma unroll 1
    for (int i = 0; i < NSTEPS; ++i) {
        // noise for this step, consumed after the barrier
        float nw0 = dWp[0], nw1 = dWp[1], nw2 = dWp[2];
        float nz0 = dZp[0], nz1 = dZp[1], nz2 = dZp[2];
        dWp += (size_t)BATCH * 3;  dZp += (size_t)BATCH * 3;

        // ---- h1 A-frags in registers: path m = 16g + ln15 ----
        float yp = __shfl(y, 16*g + ln15);
        float hh[16];
#pragma unroll
        for (int idx = 0; idx < 16; ++idx)
            hh[idx] = fmaxf(fmaf(B1c[idx], yp, fmaf(A1[idx], t, C1[idx])), 0.0f);

        union { unsigned u[4]; bf16x8 v; } af0, af1;
#pragma unroll
        for (int m = 0; m < 4; ++m) {
            af0.u[m] = packbf16(hh[2*m],     hh[2*m + 1]);
            af1.u[m] = packbf16(hh[8 + 2*m], hh[8 + 2*m + 1]);
        }

        // ---- layer-2 MFMA: D[path=16g+q4*4+r][n=16tN+ln15] ----
        float rd[4][4];
#pragma unroll
        for (int tN = 0; tN < 4; ++tN) {
            f32x4 d = { b2v[tN], b2v[tN], b2v[tN], b2v[tN] };
            d = __builtin_amdgcn_mfma_f32_16x16x32_bf16(af0.v, Bf[tN][0], d, 0, 0, 0);
            d = __builtin_amdgcn_mfma_f32_16x16x32_bf16(af1.v, Bf[tN][1], d, 0, 0, 0);
#pragma unroll
            for (int r = 0; r < 4; ++r) rd[tN][r] = fmaxf(d[r], 0.0f);
        }

        // ---- layer-3 partials + DPP row reduction + LDS exchange ----
        const int buf = i & 1;
        const bool b0 = (ln15 & 1) != 0, b1 = (ln15 & 2) != 0;
        if (s == 0) {
            float P[3][4];
#pragma unroll
            for (int c = 0; c < 3; ++c)
#pragma unroll
                for (int r = 0; r < 4; ++r) {
                    float x = rd[0][r] * w3r[c][0];
                    x = fmaf(rd[1][r], w3r[c][1], x);
                    x = fmaf(rd[2][r], w3r[c][2], x);
                    x = fmaf(rd[3][r], w3r[c][3], x);
                    P[c][r] = rowsum16(x);
                }
            float v[3];
#pragma unroll
            for (int c = 0; c < 3; ++c) {
                float a = b0 ? P[c][1] : P[c][0];
                float b = b0 ? P[c][3] : P[c][2];
                v[c] = b1 ? b : a;
            }
            if (ln15 < 4)
                pzs[buf][16*g + q4*4 + ln15] = make_float4(v[0], v[1], v[2], 0.0f);
        } else {
            float Pq[4];
#pragma unroll
            for (int r = 0; r < 4; ++r) {
                float x = rd[0][r] * w3q[0];
                x = fmaf(rd[1][r], w3q[1], x);
                x = fmaf(rd[2][r], w3q[2], x);
                x = fmaf(rd[3][r], w3q[3], x);
                Pq[r] = rowsum16(x);
            }
            float a = b0 ? Pq[1] : Pq[0];
            float b = b0 ? Pq[3] : Pq[2];
            float vq = b1 ? b : a;
            if (ln15 < 4)
                pqs[buf][16*g + q4*4 + ln15] = vq;
        }
        __syncthreads();   // the ONLY barrier per step

        // ---- epilogue (redundant on all 8 waves; path = lane) ----
        float4 zv = pzs[buf][lane];
        float  qv = pqs[buf][lane];
        float z0 = zv.x + zb30, z1 = zv.y + zb31, z2 = zv.z + zb32;
        float q  = qv + qb30;

        float dw0 = SQRTDT*nw0, dw1 = SQRTDT*nw1, dw2 = SQRTDT*nw2;
        float dz0 = SQRTDT*nz0, dz1 = SQRTDT*nz1, dz2 = SQRTDT*nz2;
        float zdw = fmaf(z2, dw2, fmaf(z1, dw1, z0*dw0));
        float zdz = fmaf(z2, dz2, fmaf(z1, dz1, z0*dz0));
        float f = 0.5f*q*q;
        Yv = Yv - f*DT_ + zdw;
        float r = zdw - zdz;             // residual: (Y - f*DT) cancels
        acc = fmaf(r, r, acc);
        y = y + q*DT_ + SIGMA0_*(dw0 + dw1 + dw2);
        t += DT_;
    }

    float dterm = Yv - y*y;
    acc = fmaf(dterm, dterm, acc);

    if (w == 0) {                        // all waves hold identical acc
        float val = acc;
#pragma unroll
        for (int off = 1; off < 64; off <<= 1) val += __shfl_xor(val, off);
        if (lane == 0) atomicAdd(out, val * (1.0f / BATCH));
    }
}

extern "C" void kernel_launch(void* const* d_in, const int* in_sizes, int n_in,
                              void* d_out, int out_size, void* d_ws, size_t ws_size,
                              hipStream_t stream)
{
    zero_out_kernel<<<1, 64, 0, stream>>>((float*)d_out);
    deepbsde_kernel<<<256, 512, 0, stream>>>(
        (const float*)d_in[0],  (const float*)d_in[1],
        (const float*)d_in[2],  (const float*)d_in[3],
        (const float*)d_in[4],  (const float*)d_in[5],
        (const float*)d_in[6],  (const float*)d_in[7],
        (const float*)d_in[8],  (const float*)d_in[9],
        (const float*)d_in[10], (const float*)d_in[11],
        (const float*)d_in[12], (const float*)d_in[13],
        (const float*)d_in[14], (const float*)d_in[15],
        (float*)d_out);
}

// Round 7
// 196.666 us; speedup vs baseline: 8.9674x; 1.0736x over previous
//
#include <hip/hip_runtime.h>
#include <hip/hip_bf16.h>

#define BATCH   16384
#define NSTEPS  100
#define DT_     0.01f
#define SQRTDT  0.1f
#define SIGMA0_ 0.5f

typedef short     bf16x8 __attribute__((ext_vector_type(8)));
typedef _Float16  f16x4  __attribute__((ext_vector_type(4)));
typedef float     f32x4  __attribute__((ext_vector_type(4)));

__global__ void zero_out_kernel(float* out) { if (threadIdx.x == 0) out[0] = 0.0f; }

static __device__ __forceinline__ unsigned packbf16(float a, float b) {
    union { __hip_bfloat162 h; unsigned u; } cv;
    cv.h = __float22bfloat162_rn(make_float2(a, b));
    return cv.u;
}
static __device__ __forceinline__ unsigned short bf16bits(float x) {
    union { __hip_bfloat16 h; unsigned short u; } cv;
    cv.h = __float2bfloat16(x);
    return cv.u;
}

// Block: 512 thr = 8 waves, 64 paths. Wave w: MLP s=w>>2, path-group g=w&3
// (paths 16g..16g+15, path = 16g + (lane&15); the 4 lane-quads replicate).
// Layer-2: Dt[n][path] = mfma16x16x32_bf16(A=W2^T frag, B=h1 frag) x2 per
// n-tile — output rows are neurons, cols are paths. That C-layout IS the
// 16x16x16 A/B fragment layout, so layer-3 runs as 4 chained
// mfma_f32_16x16x16_f16(A=W3^T, B=relu(Dt)) — no DPP reduction, no
// transpose. Exchange via stride-4B SoA LDS (conflict-free), 1 barrier/step.
__launch_bounds__(512)
__global__ void deepbsde_kernel(
    const float* __restrict__ y0,  const float* __restrict__ Y0,
    const float* __restrict__ zW1, const float* __restrict__ zb1,
    const float* __restrict__ zW2, const float* __restrict__ zb2,
    const float* __restrict__ zW3, const float* __restrict__ zb3,
    const float* __restrict__ qW1, const float* __restrict__ qb1,
    const float* __restrict__ qW2, const float* __restrict__ qb2,
    const float* __restrict__ qW3, const float* __restrict__ qb3,
    const float* __restrict__ dW,  const float* __restrict__ dZ,
    float* __restrict__ out)
{
    __shared__ float pz0[2][64], pz1[2][64], pz2[2][64], pqv[2][64];

    const int tid  = threadIdx.x;
    const int lane = tid & 63;
    const int w    = tid >> 6;       // 0..7
    const int s    = w >> 2;         // 0 = z-MLP, 1 = q-MLP
    const int g    = w & 3;          // path-group
    const int ln15 = lane & 15, q4 = lane >> 4;
    const int pl   = 16*g + ln15;                 // path within block
    const int pgl  = (blockIdx.x << 6) + pl;      // global path

    const float* __restrict__ W1s = s ? qW1 : zW1;
    const float* __restrict__ b1s = s ? qb1 : zb1;
    const float* __restrict__ W2s = s ? qW2 : zW2;
    const float* __restrict__ b2s = s ? qb2 : zb2;

    // layer-1 consts at this lane's h1-frag k indices: k = 32f + 8q4 + j
    float A1[16], B1c[16], C1[16];
#pragma unroll
    for (int f = 0; f < 2; ++f)
#pragma unroll
        for (int j = 0; j < 8; ++j) {
            int k = 32*f + q4*8 + j;
            A1[f*8+j]  = W1s[k];
            B1c[f*8+j] = W1s[64 + k];
            C1[f*8+j]  = b1s[k];
        }

    // resident W2^T A-frags: A[m = n' = 16tN+ln15][k = 32f+8q4+j]
    // (identical elements to R5/R6's B-frags — only the operand role changes)
    bf16x8 Af[4][2];
#pragma unroll
    for (int tN = 0; tN < 4; ++tN)
#pragma unroll
        for (int f = 0; f < 2; ++f)
#pragma unroll
            for (int j = 0; j < 8; ++j)
                Af[tN][f][j] = (short)bf16bits(W2s[(32*f + q4*8 + j)*64 + 16*tN + ln15]);

    // layer-2 bias along Dt rows: row n' = 16tN + 4q4 + r (same for all cols)
    float b2v[4][4];
#pragma unroll
    for (int tN = 0; tN < 4; ++tN)
#pragma unroll
        for (int r = 0; r < 4; ++r) b2v[tN][r] = b2s[16*tN + 4*q4 + r];

    // layer-3 W3^T A-frags (16x16x16): A[m = c = ln15][k = n = 16tN+4q4+j]
    f16x4 A3[4];
#pragma unroll
    for (int tN = 0; tN < 4; ++tN) {
        float v[4];
#pragma unroll
        for (int j = 0; j < 4; ++j) {
            int n = 16*tN + 4*q4 + j;
            v[j] = (s == 0) ? (ln15 < 3 ? zW3[n*3 + ln15] : 0.0f)
                            : (ln15 == 0 ? qW3[n] : 0.0f);
        }
        A3[tN] = (f16x4){(_Float16)v[0], (_Float16)v[1],
                         (_Float16)v[2], (_Float16)v[3]};
    }

    float y  = y0[0];            // this lane's path state
    float Yv = Y0[0];
    float t  = 0.0f, acc = 0.0f;
    const float zb30 = zb3[0], zb31 = zb3[1], zb32 = zb3[2], qb30 = qb3[0];

    const float* dWp = dW + (size_t)pgl * 3;
    const float* dZp = dZ + (size_t)pgl * 3;

#pragma unroll 1
    for (int i = 0; i < NSTEPS; ++i) {
        float nw0 = dWp[0], nw1 = dWp[1], nw2 = dWp[2];
        float nz0 = dZp[0], nz1 = dZp[1], nz2 = dZp[2];
        dWp += (size_t)BATCH * 3;  dZp += (size_t)BATCH * 3;

        // ---- h1 B-frag for path pl (k = 32f + 8q4 + j) ----
        float hh[16];
#pragma unroll
        for (int idx = 0; idx < 16; ++idx)
            hh[idx] = fmaxf(fmaf(B1c[idx], y, fmaf(A1[idx], t, C1[idx])), 0.0f);
        union { unsigned u[4]; bf16x8 v; } bf0, bf1;
#pragma unroll
        for (int m = 0; m < 4; ++m) {
            bf0.u[m] = packbf16(hh[2*m],     hh[2*m + 1]);
            bf1.u[m] = packbf16(hh[8 + 2*m], hh[8 + 2*m + 1]);
        }

        // ---- layer-2: Dt[n'][path], rows=neurons, cols=paths; relu -> f16 ----
        f16x4 B3[4];
#pragma unroll
        for (int tN = 0; tN < 4; ++tN) {
            f32x4 d = { b2v[tN][0], b2v[tN][1], b2v[tN][2], b2v[tN][3] };
            d = __builtin_amdgcn_mfma_f32_16x16x32_bf16(Af[tN][0], bf0.v, d, 0, 0, 0);
            d = __builtin_amdgcn_mfma_f32_16x16x32_bf16(Af[tN][1], bf1.v, d, 0, 0, 0);
            B3[tN] = (f16x4){(_Float16)fmaxf(d[0], 0.0f), (_Float16)fmaxf(d[1], 0.0f),
                             (_Float16)fmaxf(d[2], 0.0f), (_Float16)fmaxf(d[3], 0.0f)};
        }

        // ---- layer-3: P[c][path] = sum_tN mfma16x16x16(W3^T, relu(Dt)) ----
        f32x4 P = {0.0f, 0.0f, 0.0f, 0.0f};
#pragma unroll
        for (int tN = 0; tN < 4; ++tN)
            P = __builtin_amdgcn_mfma_f32_16x16x16f16(A3[tN], B3[tN], P, 0, 0, 0);

        // rows c = 4q4 + r, col = ln15 = path -> q4==0 lanes hold c=0..3
        const int buf = i & 1;
        if (q4 == 0) {
            if (s == 0) {
                pz0[buf][pl] = P[0];
                pz1[buf][pl] = P[1];
                pz2[buf][pl] = P[2];
            } else {
                pqv[buf][pl] = P[0];
            }
        }
        __syncthreads();   // the only barrier per step

        // ---- epilogue for this lane's path ----
        float z0 = pz0[buf][pl] + zb30;
        float z1 = pz1[buf][pl] + zb31;
        float z2 = pz2[buf][pl] + zb32;
        float q  = pqv[buf][pl] + qb30;

        float dw0 = SQRTDT*nw0, dw1 = SQRTDT*nw1, dw2 = SQRTDT*nw2;
        float dz0 = SQRTDT*nz0, dz1 = SQRTDT*nz1, dz2 = SQRTDT*nz2;
        float zdw = fmaf(z2, dw2, fmaf(z1, dw1, z0*dw0));
        float zdz = fmaf(z2, dz2, fmaf(z1, dz1, z0*dz0));
        float f = 0.5f*q*q;
        Yv = Yv - f*DT_ + zdw;
        float r = zdw - zdz;             // residual: (Y - f*DT) cancels
        acc = fmaf(r, r, acc);
        y = y + q*DT_ + SIGMA0_*(dw0 + dw1 + dw2);
        t += DT_;
    }

    float dterm = Yv - y*y;
    acc = fmaf(dterm, dterm, acc);

    // each path counted once: z-waves' q4==0 lanes
    if (s == 0) {
        float val = (q4 == 0) ? acc : 0.0f;
#pragma unroll
        for (int off = 1; off < 64; off <<= 1) val += __shfl_xor(val, off);
        if (lane == 0) atomicAdd(out, val * (1.0f / BATCH));
    }
}

extern "C" void kernel_launch(void* const* d_in, const int* in_sizes, int n_in,
                              void* d_out, int out_size, void* d_ws, size_t ws_size,
                              hipStream_t stream)
{
    zero_out_kernel<<<1, 64, 0, stream>>>((float*)d_out);
    deepbsde_kernel<<<256, 512, 0, stream>>>(
        (const float*)d_in[0],  (const float*)d_in[1],
        (const float*)d_in[2],  (const float*)d_in[3],
        (const float*)d_in[4],  (const float*)d_in[5],
        (const float*)d_in[6],  (const float*)d_in[7],
        (const float*)d_in[8],  (const float*)d_in[9],
        (const float*)d_in[10], (const float*)d_in[11],
        (const float*)d_in[12], (const float*)d_in[13],
        (const float*)d_in[14], (const float*)d_in[15],
        (float*)d_out);
}